// Round 22
// baseline (94.763 us; speedup 1.0000x reference)
//
#include <hip/hip_runtime.h>

typedef __bf16 bf16x8 __attribute__((ext_vector_type(8)));
typedef __bf16 bf16x4 __attribute__((ext_vector_type(4)));
typedef float f32x4 __attribute__((ext_vector_type(4)));
typedef unsigned short u16;
typedef unsigned int u32;
typedef u32 u32x4 __attribute__((ext_vector_type(4)));

__device__ __forceinline__ u16 f2bf(float f) {
  u32 u = __builtin_bit_cast(u32, f);
  u += 0x7fffu + ((u >> 16) & 1u);
  return (u16)(u >> 16);
}

__device__ __forceinline__ u32 cvt_pk_bf16(float lo, float hi) {
  u32 r;
  asm("v_cvt_pk_bf16_f32 %0, %1, %2" : "=v"(r) : "v"(lo), "v"(hi));
  return r;
}

__device__ __forceinline__ float ex2(float x) {
  float r;
  asm("v_exp_f32 %0, %1" : "=v"(r) : "v"(x));
  return r;
}

__device__ __forceinline__ void gl_lds16(const u16* g, u16* l) {
  __builtin_amdgcn_global_load_lds(
      (const __attribute__((address_space(1))) u32*)g,
      (__attribute__((address_space(3))) u32*)l, 16, 0, 0);
}

// LDS transpose read; per-lane address p = base + lane*4 elems (verified R4).
__device__ __forceinline__ bf16x4 tr16(const u16* p) {
  bf16x4 r;
  auto lp = (const __attribute__((address_space(3))) u16*)p;
  asm volatile("ds_read_b64_tr_b16 %0, %1" : "=&v"(r) : "v"(lp));
  return r;
}

// ---------------- fused prep: x cast + Wqkv transpose + Wproj transpose -------
__global__ __launch_bounds__(256) void k_prep(const float* __restrict__ x,
                                              u16* __restrict__ Xb,
                                              const float* __restrict__ Wqkv,
                                              u16* __restrict__ Wqt,
                                              const float* __restrict__ Wproj,
                                              u16* __restrict__ Wpt) {
  __shared__ float tile[32][33];
  const int bid = blockIdx.x;
  if (bid < 2048) {
    int i = bid * 256 + threadIdx.x;
    const float4* p = (const float4*)x + (size_t)i * 2;
    float4 a = p[0], b = p[1];
    u16 r[8] = {f2bf(a.x), f2bf(a.y), f2bf(a.z), f2bf(a.w),
                f2bf(b.x), f2bf(b.y), f2bf(b.z), f2bf(b.w)};
    ((uint4*)Xb)[i] = *(const uint4*)r;
    return;
  }
  const float* in;
  u16* out;
  int K, N, n0, k0;
  if (bid < 5120) {
    in = Wqkv;
    out = Wqt;
    K = 1024;
    N = 3072;
    int idx = bid - 2048;
    n0 = (idx % 96) * 32;
    k0 = (idx / 96) * 32;
  } else {
    in = Wproj;
    out = Wpt;
    K = 1024;
    N = 1024;
    int idx = bid - 5120;
    n0 = (idx & 31) * 32;
    k0 = (idx >> 5) * 32;
  }
  int c = threadIdx.x & 31, r0 = (threadIdx.x >> 5) * 4;
#pragma unroll
  for (int rr = 0; rr < 4; ++rr) {
    int r = r0 + rr;
    tile[r][c] = in[(size_t)(k0 + r) * N + n0 + c];
  }
  __syncthreads();
#pragma unroll
  for (int rr = 0; rr < 4; ++rr) {
    int r = r0 + rr;
    out[(size_t)(n0 + r) * K + k0 + c] = f2bf(tile[c][r]);
  }
}

// ---------------- QKV GEMM (R13/R15-verified): 128x128, BK=64, LDS union ------
__global__ __launch_bounds__(256) void k_gemm0(const u16* __restrict__ A,
                                               const u16* __restrict__ Bt,
                                               u16* __restrict__ Qp, u16* __restrict__ Kp,
                                               u16* __restrict__ Vp, int K) {
  __shared__ char smem[128 * 136 * 2];  // 34.8 KB
  u16* As = (u16*)smem;
  u16* Bs = (u16*)(smem + 16384);
  u16* Cs = (u16*)smem;
  const int tid = threadIdx.x;
  const int lane = tid & 63, wave = tid >> 6;
  const int l15 = lane & 15, l4 = lane >> 4;
  const int wr = wave >> 1, wc = wave & 1;
  const int tm = blockIdx.y, tn = blockIdx.x;

  int srow[4], scol[4];
#pragma unroll
  for (int i = 0; i < 4; ++i) {
    srow[i] = wave * 32 + i * 8 + (lane >> 3);
    scol[i] = ((lane & 7) ^ (srow[i] & 7)) * 8;
  }

  const f32x4 fz = {0.f, 0.f, 0.f, 0.f};
  f32x4 acc[4][4];
#pragma unroll
  for (int a = 0; a < 4; ++a)
#pragma unroll
    for (int b = 0; b < 4; ++b) acc[a][b] = fz;

  const int nk = K >> 6;
  for (int kt = 0; kt < nk; ++kt) {
#pragma unroll
    for (int i = 0; i < 4; ++i)
      gl_lds16(A + (size_t)(tm * 128 + srow[i]) * K + kt * 64 + scol[i],
               &As[(wave * 4 + i) * 512]);
#pragma unroll
    for (int i = 0; i < 4; ++i)
      gl_lds16(Bt + (size_t)(tn * 128 + srow[i]) * K + kt * 64 + scol[i],
               &Bs[(wave * 4 + i) * 512]);
    __syncthreads();
    bf16x8 af[2][4], bfr[2][4];
#pragma unroll
    for (int s = 0; s < 2; ++s) {
#pragma unroll
      for (int mi = 0; mi < 4; ++mi) {
        int row = wr * 64 + mi * 16 + l15;
        int pch = (s * 4 + l4) ^ (row & 7);
        af[s][mi] = *(const bf16x8*)&As[row * 64 + pch * 8];
      }
#pragma unroll
      for (int ni = 0; ni < 4; ++ni) {
        int row = wc * 64 + ni * 16 + l15;
        int pch = (s * 4 + l4) ^ (row & 7);
        bfr[s][ni] = *(const bf16x8*)&Bs[row * 64 + pch * 8];
      }
    }
    __builtin_amdgcn_s_setprio(1);
#pragma unroll
    for (int s = 0; s < 2; ++s)
#pragma unroll
      for (int mi = 0; mi < 4; ++mi)
#pragma unroll
        for (int ni = 0; ni < 4; ++ni)
          acc[mi][ni] = __builtin_amdgcn_mfma_f32_16x16x32_bf16(af[s][mi], bfr[s][ni],
                                                                acc[mi][ni], 0, 0, 0);
    __builtin_amdgcn_s_setprio(0);
    __syncthreads();
  }

#pragma unroll
  for (int ni = 0; ni < 4; ++ni) {
    int colb = wc * 64 + ni * 16;
    float scl = ((tn * 128 + colb) >> 10) == 0 ? 0.180336880f : 1.0f;  // 0.125*log2e
#pragma unroll
    for (int mi = 0; mi < 4; ++mi)
#pragma unroll
      for (int r = 0; r < 4; ++r) {
        int rowb = wr * 64 + mi * 16 + l4 * 4 + r;
        Cs[rowb * 136 + colb + l15] = f2bf(acc[mi][ni][r] * scl);
      }
  }
  __syncthreads();
#pragma unroll
  for (int pass = 0; pass < 8; ++pass) {
    int rowb = pass * 16 + (tid >> 4);
    int colb = (tid & 15) * 8;
    uint4 v = *(const uint4*)&Cs[rowb * 136 + colb];
    int rowg = tm * 128 + rowb;
    int b = rowg >> 11, t = rowg & 2047;
    int gcol = tn * 128 + colb;
    int which = gcol >> 10;
    int d = gcol & 1023;
    int h = d >> 6, hd = d & 63;
    u16* dst = which == 0 ? Qp : (which == 1 ? Kp : Vp);
    *(uint4*)&dst[(size_t)(((b * 16 + h) * 2048 + t) * 64 + hd)] = v;
  }
}

// ---------------- projection GEMM: 128(M)x64(N), 512 blocks, coalesced f32 epi ----
__global__ __launch_bounds__(256) void k_gemm1(const u16* __restrict__ A,
                                               const u16* __restrict__ Bt,
                                               float* __restrict__ Cf, int K) {
  __shared__ char smem1[128 * 68 * 4];  // 34.8 KB union
  u16* As = (u16*)smem1;
  u16* Bs = (u16*)(smem1 + 16384);
  float* Cs = (float*)smem1;
  const int tid = threadIdx.x;
  const int lane = tid & 63, wave = tid >> 6;
  const int l15 = lane & 15, l4 = lane >> 4;
  const int wr = wave >> 1, wc = wave & 1;
  const int tm = blockIdx.y, tn = blockIdx.x;  // grid (16, 32)

  int srowA[4], scolA[4], srowB[2], scolB[2];
#pragma unroll
  for (int i = 0; i < 4; ++i) {
    srowA[i] = wave * 32 + i * 8 + (lane >> 3);
    scolA[i] = ((lane & 7) ^ (srowA[i] & 7)) * 8;
  }
#pragma unroll
  for (int i = 0; i < 2; ++i) {
    srowB[i] = wave * 16 + i * 8 + (lane >> 3);
    scolB[i] = ((lane & 7) ^ (srowB[i] & 7)) * 8;
  }

  const f32x4 fz = {0.f, 0.f, 0.f, 0.f};
  f32x4 acc[4][2];
#pragma unroll
  for (int a = 0; a < 4; ++a)
#pragma unroll
    for (int b = 0; b < 2; ++b) acc[a][b] = fz;

  const int nk = K >> 6;
  for (int kt = 0; kt < nk; ++kt) {
#pragma unroll
    for (int i = 0; i < 4; ++i)
      gl_lds16(A + (size_t)(tm * 128 + srowA[i]) * K + kt * 64 + scolA[i],
               &As[(wave * 4 + i) * 512]);
#pragma unroll
    for (int i = 0; i < 2; ++i)
      gl_lds16(Bt + (size_t)(tn * 64 + srowB[i]) * K + kt * 64 + scolB[i],
               &Bs[(wave * 2 + i) * 512]);
    __syncthreads();
    bf16x8 af[2][4], bfr[2][2];
#pragma unroll
    for (int s = 0; s < 2; ++s) {
#pragma unroll
      for (int mi = 0; mi < 4; ++mi) {
        int row = wr * 64 + mi * 16 + l15;
        int pch = (s * 4 + l4) ^ (row & 7);
        af[s][mi] = *(const bf16x8*)&As[row * 64 + pch * 8];
      }
#pragma unroll
      for (int ni = 0; ni < 2; ++ni) {
        int row = wc * 32 + ni * 16 + l15;
        int pch = (s * 4 + l4) ^ (row & 7);
        bfr[s][ni] = *(const bf16x8*)&Bs[row * 64 + pch * 8];
      }
    }
    __builtin_amdgcn_s_setprio(1);
#pragma unroll
    for (int s = 0; s < 2; ++s)
#pragma unroll
      for (int mi = 0; mi < 4; ++mi)
#pragma unroll
        for (int ni = 0; ni < 2; ++ni)
          acc[mi][ni] = __builtin_amdgcn_mfma_f32_16x16x32_bf16(af[s][mi], bfr[s][ni],
                                                                acc[mi][ni], 0, 0, 0);
    __builtin_amdgcn_s_setprio(0);
    __syncthreads();
  }

#pragma unroll
  for (int mi = 0; mi < 4; ++mi)
#pragma unroll
    for (int ni = 0; ni < 2; ++ni)
#pragma unroll
      for (int r = 0; r < 4; ++r) {
        int rowb = wr * 64 + mi * 16 + l4 * 4 + r;
        Cs[rowb * 68 + wc * 32 + ni * 16 + l15] = acc[mi][ni][r];
      }
  __syncthreads();
#pragma unroll
  for (int pass = 0; pass < 8; ++pass) {
    int rowb = pass * 16 + (tid >> 4);
    int colb = (tid & 15) * 4;
    float4 v = *(const float4*)&Cs[rowb * 68 + colb];
    *(float4*)&Cf[(size_t)(tm * 128 + rowb) * 1024 + tn * 64 + colb] = v;
  }
}

// ---------------- causal flash attention (v12: 9 slots/block) ----------
// Slot-floor model: pack tiles SEQUENTIALLY per slot (registers stay per-tile).
// Phase 1: pairs of A+B tiles (ceil((pp+1)/2) slots); phase 2: quads of A
// tiles (ceil((31-2pp)/4) slots); total = 9 slots for every pp.
// Conservative sync: vmcnt(0)+barrier at slot top; barrier+restage at bottom
// (full drains measured ~free with 2 blocks/CU -- R7/R17). Buffers = kt&3,
// stage-ahead window <= 4 via monotone stageNext.
__global__ __launch_bounds__(256) void k_attn(const u16* __restrict__ Q,
                                              const u16* __restrict__ K,
                                              const u16* __restrict__ V,
                                              u16* __restrict__ Y) {
  __shared__ u16 Kl[4][64 * 64];
  __shared__ u16 Vtr[4][64 * 64];
  const int tid = threadIdx.x, lane = tid & 63, wave = tid >> 6;
  const int l15 = lane & 15, l4 = lane >> 4;
  const int L = blockIdx.y * 16 + blockIdx.x;
  const int g = L & 7, j = L >> 3;
  const int bh = (g << 2) + (j >> 4);   // XCD-grouped (R18): 4 bh per XCD
  const int pp = j & 15;
  const int qtA = 31 - pp, qtB = pp;
  const u16* Qb = Q + (size_t)bh * 2048 * 64;
  const u16* Kb = K + (size_t)bh * 2048 * 64;
  const u16* Vb = V + (size_t)bh * 2048 * 64;
  const int b = bh >> 4, h = bh & 15;
  const f32x4 fz = {0.f, 0.f, 0.f, 0.f};

  const int kk0 = wave * 16 + (lane >> 3);
  const int kk1 = kk0 + 8;
  const int lcol0 = ((lane & 7) ^ (kk0 & 7)) * 8;
  const int lcol1 = ((lane & 7) ^ (kk1 & 7)) * 8;
  int vk[2], vhd[2];
#pragma unroll
  for (int i = 0; i < 2; ++i) {
    int o = (wave * 2 + i) * 512 + lane * 8;
    vk[i] = ((o >> 6) & 15) * 4 + ((o >> 4) & 3);
    vhd[i] = ((o >> 10) << 4) + (o & 8);
  }

  auto stage = [&](int buf, int kt) {
    gl_lds16(Kb + (size_t)(kt * 64 + kk0) * 64 + lcol0, &Kl[buf][(wave * 2 + 0) * 512]);
    gl_lds16(Kb + (size_t)(kt * 64 + kk1) * 64 + lcol1, &Kl[buf][(wave * 2 + 1) * 512]);
    gl_lds16(Vb + (size_t)(kt * 64 + vk[0]) * 64 + vhd[0], &Vtr[buf][(wave * 2 + 0) * 512]);
    gl_lds16(Vb + (size_t)(kt * 64 + vk[1]) * 64 + vhd[1], &Vtr[buf][(wave * 2 + 1) * 512]);
  };

  auto qk = [&](int buf, const bf16x8* qf, f32x4* accS) {
#pragma unroll
    for (int s = 0; s < 2; ++s)
#pragma unroll
      for (int nb = 0; nb < 4; ++nb) {
        int kk = nb * 16 + l15;
        int ch = (s * 4 + l4) ^ (kk & 7);
        bf16x8 kf = *(const bf16x8*)&Kl[buf][kk * 64 + ch * 8];
        accS[nb] = __builtin_amdgcn_mfma_f32_16x16x32_bf16(kf, qf[s], accS[nb], 0, 0, 0);
      }
  };
  // batched PV: 16 tr16, ONE lgkm wait, 16 MFMA (R21-verified)
  auto pv = [&](int buf, const bf16x8* pf, f32x4* accO) {
    bf16x8 vf[2][4];
#pragma unroll
    for (int s = 0; s < 2; ++s)
#pragma unroll
      for (int hb = 0; hb < 4; ++hb) {
        bf16x4 ta = tr16(&Vtr[buf][(hb * 16 + s * 8) * 64 + lane * 4]);
        bf16x4 tb = tr16(&Vtr[buf][(hb * 16 + s * 8 + 4) * 64 + lane * 4]);
        vf[s][hb] = __builtin_shufflevector(ta, tb, 0, 1, 2, 3, 4, 5, 6, 7);
      }
    asm volatile("s_waitcnt lgkmcnt(0)" ::: "memory");
    __builtin_amdgcn_sched_barrier(0);
    __builtin_amdgcn_s_setprio(1);
#pragma unroll
    for (int s = 0; s < 2; ++s)
#pragma unroll
      for (int hb = 0; hb < 4; ++hb)
        accO[hb] = __builtin_amdgcn_mfma_f32_16x16x32_bf16(vf[s][hb], pf[s], accO[hb], 0, 0, 0);
    __builtin_amdgcn_s_setprio(0);
  };

  bf16x8 qfA[2], qfB[2];
  {
    int qrA = qtA * 64 + wave * 16 + l15;
    int qrB = qtB * 64 + wave * 16 + l15;
    qfA[0] = *(const bf16x8*)&Qb[(size_t)qrA * 64 + l4 * 8];
    qfA[1] = *(const bf16x8*)&Qb[(size_t)qrA * 64 + 32 + l4 * 8];
    qfB[0] = *(const bf16x8*)&Qb[(size_t)qrB * 64 + l4 * 8];
    qfB[1] = *(const bf16x8*)&Qb[(size_t)qrB * 64 + 32 + l4 * 8];
  }
  f32x4 oA[4] = {fz, fz, fz, fz}, oB[4] = {fz, fz, fz, fz};
  float mA = -1e30f, lsA = 0.f, mB = -1e30f, lsB = 0.f;

  // per-tile body: A+B (phase 1), fused softmax, shared vf PV
  auto bodyAB = [&](int kt) {
    const int buf = kt & 3;
    f32x4 sA[4] = {fz, fz, fz, fz}, sB[4] = {fz, fz, fz, fz};
    __builtin_amdgcn_s_setprio(1);
#pragma unroll
    for (int s = 0; s < 2; ++s)
#pragma unroll
      for (int nb = 0; nb < 4; ++nb) {
        int kk = nb * 16 + l15;
        int ch = (s * 4 + l4) ^ (kk & 7);
        bf16x8 kf = *(const bf16x8*)&Kl[buf][kk * 64 + ch * 8];
        sA[nb] = __builtin_amdgcn_mfma_f32_16x16x32_bf16(kf, qfA[s], sA[nb], 0, 0, 0);
        sB[nb] = __builtin_amdgcn_mfma_f32_16x16x32_bf16(kf, qfB[s], sB[nb], 0, 0, 0);
      }
    __builtin_amdgcn_s_setprio(0);

    float vA[16], vB[16];
#pragma unroll
    for (int nb = 0; nb < 4; ++nb)
#pragma unroll
      for (int r = 0; r < 4; ++r) {
        vA[nb * 4 + r] = sA[nb][r];
        vB[nb * 4 + r] = sB[nb][r];
      }
    if (kt == qtB) {
      int qg = wave * 16 + l15;
#pragma unroll
      for (int i = 0; i < 16; ++i) {
        int kg = (i >> 2) * 16 + l4 * 4 + (i & 3);
        if (kg > qg) vB[i] = -1e30f;
      }
    }
    float tA[8], tB[8];
#pragma unroll
    for (int i = 0; i < 8; ++i) {
      tA[i] = fmaxf(vA[2 * i], vA[2 * i + 1]);
      tB[i] = fmaxf(vB[2 * i], vB[2 * i + 1]);
    }
#pragma unroll
    for (int i = 0; i < 4; ++i) {
      tA[i] = fmaxf(tA[i], tA[i + 4]);
      tB[i] = fmaxf(tB[i], tB[i + 4]);
    }
    float mxA = fmaxf(fmaxf(tA[0], tA[2]), fmaxf(tA[1], tA[3]));
    float mxB = fmaxf(fmaxf(tB[0], tB[2]), fmaxf(tB[1], tB[3]));
    if (!__all(fmaxf(mxA - mA, mxB - mB) <= 8.0f)) {
      float mrA = fmaxf(mxA, __shfl_xor(mxA, 16));
      float mrB = fmaxf(mxB, __shfl_xor(mxB, 16));
      mrA = fmaxf(mrA, __shfl_xor(mrA, 32));
      mrB = fmaxf(mrB, __shfl_xor(mrB, 32));
      float mnA = fmaxf(mA, mrA), mnB = fmaxf(mB, mrB);
      float aA = ex2(mA - mnA), aB = ex2(mB - mnB);
      mA = mnA;
      mB = mnB;
      lsA *= aA;
      lsB *= aB;
#pragma unroll
      for (int hb = 0; hb < 4; ++hb)
#pragma unroll
        for (int r = 0; r < 4; ++r) {
          oA[hb][r] *= aA;
          oB[hb][r] *= aB;
        }
    }
    float pA[16], pB[16];
#pragma unroll
    for (int i = 0; i < 16; ++i) {
      pA[i] = ex2(vA[i] - mA);
      pB[i] = ex2(vB[i] - mB);
    }
    float uA[8], uB[8];
#pragma unroll
    for (int i = 0; i < 8; ++i) {
      uA[i] = pA[2 * i] + pA[2 * i + 1];
      uB[i] = pB[2 * i] + pB[2 * i + 1];
    }
#pragma unroll
    for (int i = 0; i < 4; ++i) {
      uA[i] += uA[i + 4];
      uB[i] += uB[i + 4];
    }
    lsA += (uA[0] + uA[2]) + (uA[1] + uA[3]);
    lsB += (uB[0] + uB[2]) + (uB[1] + uB[3]);
    bf16x8 pfA[2], pfB[2];
#pragma unroll
    for (int s = 0; s < 2; ++s) {
      u32x4 wa, wb;
      wa.x = cvt_pk_bf16(pA[8 * s + 0], pA[8 * s + 1]);
      wb.x = cvt_pk_bf16(pB[8 * s + 0], pB[8 * s + 1]);
      wa.y = cvt_pk_bf16(pA[8 * s + 2], pA[8 * s + 3]);
      wb.y = cvt_pk_bf16(pB[8 * s + 2], pB[8 * s + 3]);
      wa.z = cvt_pk_bf16(pA[8 * s + 4], pA[8 * s + 5]);
      wb.z = cvt_pk_bf16(pB[8 * s + 4], pB[8 * s + 5]);
      wa.w = cvt_pk_bf16(pA[8 * s + 6], pA[8 * s + 7]);
      wb.w = cvt_pk_bf16(pB[8 * s + 6], pB[8 * s + 7]);
      pfA[s] = __builtin_bit_cast(bf16x8, wa);
      pfB[s] = __builtin_bit_cast(bf16x8, wb);
    }
    // shared vf PV for A and B (one lgkm wait)
    bf16x8 vf[2][4];
#pragma unroll
    for (int s = 0; s < 2; ++s)
#pragma unroll
      for (int hb = 0; hb < 4; ++hb) {
        bf16x4 ta = tr16(&Vtr[buf][(hb * 16 + s * 8) * 64 + lane * 4]);
        bf16x4 tb = tr16(&Vtr[buf][(hb * 16 + s * 8 + 4) * 64 + lane * 4]);
        vf[s][hb] = __builtin_shufflevector(ta, tb, 0, 1, 2, 3, 4, 5, 6, 7);
      }
    asm volatile("s_waitcnt lgkmcnt(0)" ::: "memory");
    __builtin_amdgcn_sched_barrier(0);
    __builtin_amdgcn_s_setprio(1);
#pragma unroll
    for (int s = 0; s < 2; ++s)
#pragma unroll
      for (int hb = 0; hb < 4; ++hb) {
        oA[hb] = __builtin_amdgcn_mfma_f32_16x16x32_bf16(vf[s][hb], pfA[s], oA[hb], 0, 0, 0);
        oB[hb] = __builtin_amdgcn_mfma_f32_16x16x32_bf16(vf[s][hb], pfB[s], oB[hb], 0, 0, 0);
      }
    __builtin_amdgcn_s_setprio(0);
  };

  // per-tile body: A only (phase 2)
  auto bodyA = [&](int kt) {
    const int buf = kt & 3;
    f32x4 sA[4] = {fz, fz, fz, fz};
    __builtin_amdgcn_s_setprio(1);
    qk(buf, qfA, sA);
    __builtin_amdgcn_s_setprio(0);
    float vA[16];
#pragma unroll
    for (int nb = 0; nb < 4; ++nb)
#pragma unroll
      for (int r = 0; r < 4; ++r) vA[nb * 4 + r] = sA[nb][r];
    if (kt == qtA) {
      int qg = wave * 16 + l15;
#pragma unroll
      for (int i = 0; i < 16; ++i) {
        int kg = (i >> 2) * 16 + l4 * 4 + (i & 3);
        if (kg > qg) vA[i] = -1e30f;
      }
    }
    float tA[8];
#pragma unroll
    for (int i = 0; i < 8; ++i) tA[i] = fmaxf(vA[2 * i], vA[2 * i + 1]);
#pragma unroll
    for (int i = 0; i < 4; ++i) tA[i] = fmaxf(tA[i], tA[i + 4]);
    float mxA = fmaxf(fmaxf(tA[0], tA[2]), fmaxf(tA[1], tA[3]));
    if (!__all(mxA <= mA + 8.0f)) {
      float mrA = fmaxf(mxA, __shfl_xor(mxA, 16));
      mrA = fmaxf(mrA, __shfl_xor(mrA, 32));
      float mnA = fmaxf(mA, mrA);
      float aA = ex2(mA - mnA);
      mA = mnA;
      lsA *= aA;
#pragma unroll
      for (int hb = 0; hb < 4; ++hb)
#pragma unroll
        for (int r = 0; r < 4; ++r) oA[hb][r] *= aA;
    }
    float pA[16];
#pragma unroll
    for (int i = 0; i < 16; ++i) pA[i] = ex2(vA[i] - mA);
    float uA[8];
#pragma unroll
    for (int i = 0; i < 8; ++i) uA[i] = pA[2 * i] + pA[2 * i + 1];
#pragma unroll
    for (int i = 0; i < 4; ++i) uA[i] += uA[i + 4];
    lsA += (uA[0] + uA[2]) + (uA[1] + uA[3]);
    bf16x8 pfA[2];
#pragma unroll
    for (int s = 0; s < 2; ++s) {
      u32x4 wa;
      wa.x = cvt_pk_bf16(pA[8 * s + 0], pA[8 * s + 1]);
      wa.y = cvt_pk_bf16(pA[8 * s + 2], pA[8 * s + 3]);
      wa.z = cvt_pk_bf16(pA[8 * s + 4], pA[8 * s + 5]);
      wa.w = cvt_pk_bf16(pA[8 * s + 6], pA[8 * s + 7]);
      pfA[s] = __builtin_bit_cast(bf16x8, wa);
    }
    pv(buf, pfA, oA);
  };

  // prologue: tiles 0..3 into bufs 0..3 (qtA >= 16 always)
#pragma unroll
  for (int t = 0; t < 4; ++t) stage(t, t);
  int stageNext = 4;
  int consumed = 0;

  // ======== phase 1: pairs of A+B tiles ========
#pragma unroll 1
  while (consumed <= qtB) {
    int end = consumed + 2 <= qtB + 1 ? consumed + 2 : qtB + 1;
    asm volatile("s_waitcnt vmcnt(0)" ::: "memory");
    __builtin_amdgcn_s_barrier();
    __builtin_amdgcn_sched_barrier(0);
#pragma unroll 1
    for (int kt = consumed; kt < end; ++kt) bodyAB(kt);
    __builtin_amdgcn_s_barrier();
    __builtin_amdgcn_sched_barrier(0);
    consumed = end;
#pragma unroll 1
    while (stageNext < consumed + 4 && stageNext <= qtA) {
      stage(stageNext & 3, stageNext);
      ++stageNext;
    }
  }

  // ======== phase 2: quads of A tiles ========
#pragma unroll 1
  while (consumed <= qtA) {
    int end = consumed + 4 <= qtA + 1 ? consumed + 4 : qtA + 1;
    asm volatile("s_waitcnt vmcnt(0)" ::: "memory");
    __builtin_amdgcn_s_barrier();
    __builtin_amdgcn_sched_barrier(0);
#pragma unroll 1
    for (int kt = consumed; kt < end; ++kt) bodyA(kt);
    __builtin_amdgcn_s_barrier();
    __builtin_amdgcn_sched_barrier(0);
    consumed = end;
#pragma unroll 1
    while (stageNext < consumed + 4 && stageNext <= qtA) {
      stage(stageNext & 3, stageNext);
      ++stageNext;
    }
  }

  // epilogue: merge group-partial lsum (2 shuffles), divide, store
  auto epi = [&](f32x4* accO, float lsum, int qt) {
    float t = lsum + __shfl_xor(lsum, 16);
    t += __shfl_xor(t, 32);
    float inv = 1.0f / t;
    int qg = qt * 64 + wave * 16 + l15;
    u16* yrow = Y + (size_t)(b * 2048 + qg) * 1024 + h * 64;
#pragma unroll
    for (int hb = 0; hb < 4; ++hb) {
      uint2 pk;
      pk.x = cvt_pk_bf16(accO[hb][0] * inv, accO[hb][1] * inv);
      pk.y = cvt_pk_bf16(accO[hb][2] * inv, accO[hb][3] * inv);
      *(uint2*)&yrow[hb * 16 + l4 * 4] = pk;
    }
  };
  epi(oA, lsA, qtA);
  epi(oB, lsB, qtB);
}

extern "C" void kernel_launch(void* const* d_in, const int* in_sizes, int n_in,
                              void* d_out, int out_size, void* d_ws, size_t ws_size,
                              hipStream_t stream) {
  const float* x = (const float*)d_in[0];       // [2,2048,1024]
  const float* Wqkv = (const float*)d_in[1];    // [1024,3072]
  const float* Wproj = (const float*)d_in[2];   // [1024,1024]
  float* out = (float*)d_out;                   // [2,2048,1024] f32

  char* ws = (char*)d_ws;
  u16* Xb  = (u16*)(ws + 0);                    // 8 MB  [4096][1024]
  u16* Wqt = (u16*)(ws + ((size_t)8 << 20));    // 6 MB  [3072][1024]
  u16* Wpt = (u16*)(ws + ((size_t)14 << 20));   // 2 MB  [1024][1024]
  u16* Qs  = (u16*)(ws + ((size_t)16 << 20));   // 8 MB  [2,16,2048,64]
  u16* Ks  = (u16*)(ws + ((size_t)24 << 20));   // 8 MB
  u16* Vs  = (u16*)(ws + ((size_t)32 << 20));   // 8 MB
  u16* Yb  = (u16*)(ws + ((size_t)40 << 20));   // 8 MB  [4096][1024]

  k_prep<<<6144, 256, 0, stream>>>(x, Xb, Wqkv, Wqt, Wproj, Wpt);
  k_gemm0<<<dim3(24, 32), 256, 0, stream>>>(Xb, Wqt, Qs, Ks, Vs, 1024);
  k_attn<<<dim3(16, 32), 256, 0, stream>>>(Qs, Ks, Vs, Yb);
  k_gemm1<<<dim3(16, 32), 256, 0, stream>>>(Yb, Wpt, out, 1024);
}

// Round 23
// 91.429 us; speedup vs baseline: 1.0365x; 1.0365x over previous
//
#include <hip/hip_runtime.h>

typedef __bf16 bf16x8 __attribute__((ext_vector_type(8)));
typedef __bf16 bf16x4 __attribute__((ext_vector_type(4)));
typedef float f32x4 __attribute__((ext_vector_type(4)));
typedef unsigned short u16;
typedef unsigned int u32;
typedef u32 u32x4 __attribute__((ext_vector_type(4)));

__device__ __forceinline__ u16 f2bf(float f) {
  u32 u = __builtin_bit_cast(u32, f);
  u += 0x7fffu + ((u >> 16) & 1u);
  return (u16)(u >> 16);
}

__device__ __forceinline__ u32 cvt_pk_bf16(float lo, float hi) {
  u32 r;
  asm("v_cvt_pk_bf16_f32 %0, %1, %2" : "=v"(r) : "v"(lo), "v"(hi));
  return r;
}

__device__ __forceinline__ float ex2(float x) {
  float r;
  asm("v_exp_f32 %0, %1" : "=v"(r) : "v"(x));
  return r;
}

__device__ __forceinline__ void gl_lds16(const u16* g, u16* l) {
  __builtin_amdgcn_global_load_lds(
      (const __attribute__((address_space(1))) u32*)g,
      (__attribute__((address_space(3))) u32*)l, 16, 0, 0);
}

// LDS transpose read; per-lane address p = base + lane*4 elems (verified R4).
__device__ __forceinline__ bf16x4 tr16(const u16* p) {
  bf16x4 r;
  auto lp = (const __attribute__((address_space(3))) u16*)p;
  asm volatile("ds_read_b64_tr_b16 %0, %1" : "=&v"(r) : "v"(lp));
  return r;
}

// ---------------- fused prep: x cast + Wqkv transpose + Wproj transpose -------
__global__ __launch_bounds__(256) void k_prep(const float* __restrict__ x,
                                              u16* __restrict__ Xb,
                                              const float* __restrict__ Wqkv,
                                              u16* __restrict__ Wqt,
                                              const float* __restrict__ Wproj,
                                              u16* __restrict__ Wpt) {
  __shared__ float tile[32][33];
  const int bid = blockIdx.x;
  if (bid < 2048) {
    int i = bid * 256 + threadIdx.x;
    const float4* p = (const float4*)x + (size_t)i * 2;
    float4 a = p[0], b = p[1];
    u16 r[8] = {f2bf(a.x), f2bf(a.y), f2bf(a.z), f2bf(a.w),
                f2bf(b.x), f2bf(b.y), f2bf(b.z), f2bf(b.w)};
    ((uint4*)Xb)[i] = *(const uint4*)r;
    return;
  }
  const float* in;
  u16* out;
  int K, N, n0, k0;
  if (bid < 5120) {
    in = Wqkv;
    out = Wqt;
    K = 1024;
    N = 3072;
    int idx = bid - 2048;
    n0 = (idx % 96) * 32;
    k0 = (idx / 96) * 32;
  } else {
    in = Wproj;
    out = Wpt;
    K = 1024;
    N = 1024;
    int idx = bid - 5120;
    n0 = (idx & 31) * 32;
    k0 = (idx >> 5) * 32;
  }
  int c = threadIdx.x & 31, r0 = (threadIdx.x >> 5) * 4;
#pragma unroll
  for (int rr = 0; rr < 4; ++rr) {
    int r = r0 + rr;
    tile[r][c] = in[(size_t)(k0 + r) * N + n0 + c];
  }
  __syncthreads();
#pragma unroll
  for (int rr = 0; rr < 4; ++rr) {
    int r = r0 + rr;
    out[(size_t)(n0 + r) * K + k0 + c] = f2bf(tile[c][r]);
  }
}

// ---------------- QKV GEMM (R13/R15-verified): 128x128, BK=64, LDS union ------
__global__ __launch_bounds__(256) void k_gemm0(const u16* __restrict__ A,
                                               const u16* __restrict__ Bt,
                                               u16* __restrict__ Qp, u16* __restrict__ Kp,
                                               u16* __restrict__ Vp, int K) {
  __shared__ char smem[128 * 136 * 2];  // 34.8 KB
  u16* As = (u16*)smem;                 // [128][64] (loop)
  u16* Bs = (u16*)(smem + 16384);       // [128][64] (loop)
  u16* Cs = (u16*)smem;                 // [128][136] (epilogue)
  const int tid = threadIdx.x;
  const int lane = tid & 63, wave = tid >> 6;
  const int l15 = lane & 15, l4 = lane >> 4;
  const int wr = wave >> 1, wc = wave & 1;
  const int tm = blockIdx.y, tn = blockIdx.x;

  int srow[4], scol[4];
#pragma unroll
  for (int i = 0; i < 4; ++i) {
    srow[i] = wave * 32 + i * 8 + (lane >> 3);
    scol[i] = ((lane & 7) ^ (srow[i] & 7)) * 8;
  }

  const f32x4 fz = {0.f, 0.f, 0.f, 0.f};
  f32x4 acc[4][4];
#pragma unroll
  for (int a = 0; a < 4; ++a)
#pragma unroll
    for (int b = 0; b < 4; ++b) acc[a][b] = fz;

  const int nk = K >> 6;
  for (int kt = 0; kt < nk; ++kt) {
#pragma unroll
    for (int i = 0; i < 4; ++i)
      gl_lds16(A + (size_t)(tm * 128 + srow[i]) * K + kt * 64 + scol[i],
               &As[(wave * 4 + i) * 512]);
#pragma unroll
    for (int i = 0; i < 4; ++i)
      gl_lds16(Bt + (size_t)(tn * 128 + srow[i]) * K + kt * 64 + scol[i],
               &Bs[(wave * 4 + i) * 512]);
    __syncthreads();
    bf16x8 af[2][4], bfr[2][4];
#pragma unroll
    for (int s = 0; s < 2; ++s) {
#pragma unroll
      for (int mi = 0; mi < 4; ++mi) {
        int row = wr * 64 + mi * 16 + l15;
        int pch = (s * 4 + l4) ^ (row & 7);
        af[s][mi] = *(const bf16x8*)&As[row * 64 + pch * 8];
      }
#pragma unroll
      for (int ni = 0; ni < 4; ++ni) {
        int row = wc * 64 + ni * 16 + l15;
        int pch = (s * 4 + l4) ^ (row & 7);
        bfr[s][ni] = *(const bf16x8*)&Bs[row * 64 + pch * 8];
      }
    }
    __builtin_amdgcn_s_setprio(1);
#pragma unroll
    for (int s = 0; s < 2; ++s)
#pragma unroll
      for (int mi = 0; mi < 4; ++mi)
#pragma unroll
        for (int ni = 0; ni < 4; ++ni)
          acc[mi][ni] = __builtin_amdgcn_mfma_f32_16x16x32_bf16(af[s][mi], bfr[s][ni],
                                                                acc[mi][ni], 0, 0, 0);
    __builtin_amdgcn_s_setprio(0);
    __syncthreads();
  }

#pragma unroll
  for (int ni = 0; ni < 4; ++ni) {
    int colb = wc * 64 + ni * 16;
    float scl = ((tn * 128 + colb) >> 10) == 0 ? 0.180336880f : 1.0f;  // 0.125*log2e
#pragma unroll
    for (int mi = 0; mi < 4; ++mi)
#pragma unroll
      for (int r = 0; r < 4; ++r) {
        int rowb = wr * 64 + mi * 16 + l4 * 4 + r;
        Cs[rowb * 136 + colb + l15] = f2bf(acc[mi][ni][r] * scl);
      }
  }
  __syncthreads();
#pragma unroll
  for (int pass = 0; pass < 8; ++pass) {
    int rowb = pass * 16 + (tid >> 4);
    int colb = (tid & 15) * 8;
    uint4 v = *(const uint4*)&Cs[rowb * 136 + colb];
    int rowg = tm * 128 + rowb;
    int b = rowg >> 11, t = rowg & 2047;
    int gcol = tn * 128 + colb;
    int which = gcol >> 10;
    int d = gcol & 1023;
    int h = d >> 6, hd = d & 63;
    u16* dst = which == 0 ? Qp : (which == 1 ? Kp : Vp);
    *(uint4*)&dst[(size_t)(((b * 16 + h) * 2048 + t) * 64 + hd)] = v;
  }
}

// ---------------- projection GEMM: 128(M)x64(N), 512 blocks, coalesced f32 epi ----
__global__ __launch_bounds__(256) void k_gemm1(const u16* __restrict__ A,
                                               const u16* __restrict__ Bt,
                                               float* __restrict__ Cf, int K) {
  __shared__ char smem1[128 * 68 * 4];  // 34.8 KB union
  u16* As = (u16*)smem1;                // 16 KB (loop)
  u16* Bs = (u16*)(smem1 + 16384);      // 8 KB (loop)
  float* Cs = (float*)smem1;            // [128][68] (epilogue)
  const int tid = threadIdx.x;
  const int lane = tid & 63, wave = tid >> 6;
  const int l15 = lane & 15, l4 = lane >> 4;
  const int wr = wave >> 1, wc = wave & 1;
  const int tm = blockIdx.y, tn = blockIdx.x;  // grid (16, 32)

  int srowA[4], scolA[4], srowB[2], scolB[2];
#pragma unroll
  for (int i = 0; i < 4; ++i) {
    srowA[i] = wave * 32 + i * 8 + (lane >> 3);
    scolA[i] = ((lane & 7) ^ (srowA[i] & 7)) * 8;
  }
#pragma unroll
  for (int i = 0; i < 2; ++i) {
    srowB[i] = wave * 16 + i * 8 + (lane >> 3);
    scolB[i] = ((lane & 7) ^ (srowB[i] & 7)) * 8;
  }

  const f32x4 fz = {0.f, 0.f, 0.f, 0.f};
  f32x4 acc[4][2];
#pragma unroll
  for (int a = 0; a < 4; ++a)
#pragma unroll
    for (int b = 0; b < 2; ++b) acc[a][b] = fz;

  const int nk = K >> 6;
  for (int kt = 0; kt < nk; ++kt) {
#pragma unroll
    for (int i = 0; i < 4; ++i)
      gl_lds16(A + (size_t)(tm * 128 + srowA[i]) * K + kt * 64 + scolA[i],
               &As[(wave * 4 + i) * 512]);
#pragma unroll
    for (int i = 0; i < 2; ++i)
      gl_lds16(Bt + (size_t)(tn * 64 + srowB[i]) * K + kt * 64 + scolB[i],
               &Bs[(wave * 2 + i) * 512]);
    __syncthreads();
    bf16x8 af[2][4], bfr[2][2];
#pragma unroll
    for (int s = 0; s < 2; ++s) {
#pragma unroll
      for (int mi = 0; mi < 4; ++mi) {
        int row = wr * 64 + mi * 16 + l15;
        int pch = (s * 4 + l4) ^ (row & 7);
        af[s][mi] = *(const bf16x8*)&As[row * 64 + pch * 8];
      }
#pragma unroll
      for (int ni = 0; ni < 2; ++ni) {
        int row = wc * 32 + ni * 16 + l15;
        int pch = (s * 4 + l4) ^ (row & 7);
        bfr[s][ni] = *(const bf16x8*)&Bs[row * 64 + pch * 8];
      }
    }
    __builtin_amdgcn_s_setprio(1);
#pragma unroll
    for (int s = 0; s < 2; ++s)
#pragma unroll
      for (int mi = 0; mi < 4; ++mi)
#pragma unroll
        for (int ni = 0; ni < 2; ++ni)
          acc[mi][ni] = __builtin_amdgcn_mfma_f32_16x16x32_bf16(af[s][mi], bfr[s][ni],
                                                                acc[mi][ni], 0, 0, 0);
    __builtin_amdgcn_s_setprio(0);
    __syncthreads();
  }

  // coalesced f32 epilogue via Cs re-tile (loop's trailing syncthreads guards union)
#pragma unroll
  for (int mi = 0; mi < 4; ++mi)
#pragma unroll
    for (int ni = 0; ni < 2; ++ni)
#pragma unroll
      for (int r = 0; r < 4; ++r) {
        int rowb = wr * 64 + mi * 16 + l4 * 4 + r;
        Cs[rowb * 68 + wc * 32 + ni * 16 + l15] = acc[mi][ni][r];
      }
  __syncthreads();
#pragma unroll
  for (int pass = 0; pass < 8; ++pass) {
    int rowb = pass * 16 + (tid >> 4);
    int colb = (tid & 15) * 4;
    float4 v = *(const float4*)&Cs[rowb * 68 + colb];
    *(float4*)&Cf[(size_t)(tm * 128 + rowb) * 1024 + tn * 64 + colb] = v;
  }
}

// ---------------- causal flash attention (R21-verified, best known) ----------
// XCD-grouped bh mapping: each XCD's 64 blocks cover only 4 bh (K/V 2MB < L2).
// PV: all 16 tr16 issued before ONE lgkmcnt(0) (R8-verified shape).
__global__ __launch_bounds__(256) void k_attn(const u16* __restrict__ Q,
                                              const u16* __restrict__ K,
                                              const u16* __restrict__ V,
                                              u16* __restrict__ Y) {
  __shared__ u16 Kl[4][64 * 64];
  __shared__ u16 Vtr[4][64 * 64];
  const int tid = threadIdx.x, lane = tid & 63, wave = tid >> 6;
  const int l15 = lane & 15, l4 = lane >> 4;
  const int L = blockIdx.y * 16 + blockIdx.x;
  const int g = L & 7, j = L >> 3;
  const int bh = (g << 2) + (j >> 4);
  const int pp = j & 15;
  const int qtA = 31 - pp, qtB = pp;
  const u16* Qb = Q + (size_t)bh * 2048 * 64;
  const u16* Kb = K + (size_t)bh * 2048 * 64;
  const u16* Vb = V + (size_t)bh * 2048 * 64;
  const int b = bh >> 4, h = bh & 15;
  const f32x4 fz = {0.f, 0.f, 0.f, 0.f};

  const int kk0 = wave * 16 + (lane >> 3);
  const int kk1 = kk0 + 8;
  const int lcol0 = ((lane & 7) ^ (kk0 & 7)) * 8;
  const int lcol1 = ((lane & 7) ^ (kk1 & 7)) * 8;
  int vk[2], vhd[2];
#pragma unroll
  for (int i = 0; i < 2; ++i) {
    int o = (wave * 2 + i) * 512 + lane * 8;
    vk[i] = ((o >> 6) & 15) * 4 + ((o >> 4) & 3);
    vhd[i] = ((o >> 10) << 4) + (o & 8);
  }

  auto stage = [&](int buf, int kt) {
    gl_lds16(Kb + (size_t)(kt * 64 + kk0) * 64 + lcol0, &Kl[buf][(wave * 2 + 0) * 512]);
    gl_lds16(Kb + (size_t)(kt * 64 + kk1) * 64 + lcol1, &Kl[buf][(wave * 2 + 1) * 512]);
    gl_lds16(Vb + (size_t)(kt * 64 + vk[0]) * 64 + vhd[0], &Vtr[buf][(wave * 2 + 0) * 512]);
    gl_lds16(Vb + (size_t)(kt * 64 + vk[1]) * 64 + vhd[1], &Vtr[buf][(wave * 2 + 1) * 512]);
  };

  auto qk = [&](int buf, const bf16x8* qf, f32x4* accS) {
#pragma unroll
    for (int s = 0; s < 2; ++s)
#pragma unroll
      for (int nb = 0; nb < 4; ++nb) {
        int kk = nb * 16 + l15;
        int ch = (s * 4 + l4) ^ (kk & 7);
        bf16x8 kf = *(const bf16x8*)&Kl[buf][kk * 64 + ch * 8];
        accS[nb] = __builtin_amdgcn_mfma_f32_16x16x32_bf16(kf, qf[s], accS[nb], 0, 0, 0);
      }
  };
  // batched PV: 16 tr16, ONE lgkm wait, 16 MFMA
  auto pv = [&](int buf, const bf16x8* pf, f32x4* accO) {
    bf16x8 vf[2][4];
#pragma unroll
    for (int s = 0; s < 2; ++s)
#pragma unroll
      for (int hb = 0; hb < 4; ++hb) {
        bf16x4 ta = tr16(&Vtr[buf][(hb * 16 + s * 8) * 64 + lane * 4]);
        bf16x4 tb = tr16(&Vtr[buf][(hb * 16 + s * 8 + 4) * 64 + lane * 4]);
        vf[s][hb] = __builtin_shufflevector(ta, tb, 0, 1, 2, 3, 4, 5, 6, 7);
      }
    asm volatile("s_waitcnt lgkmcnt(0)" ::: "memory");
    __builtin_amdgcn_sched_barrier(0);
    __builtin_amdgcn_s_setprio(1);
#pragma unroll
    for (int s = 0; s < 2; ++s)
#pragma unroll
      for (int hb = 0; hb < 4; ++hb)
        accO[hb] = __builtin_amdgcn_mfma_f32_16x16x32_bf16(vf[s][hb], pf[s], accO[hb], 0, 0, 0);
    __builtin_amdgcn_s_setprio(0);
  };

  bf16x8 qfA[2], qfB[2];
  {
    int qrA = qtA * 64 + wave * 16 + l15;
    int qrB = qtB * 64 + wave * 16 + l15;
    qfA[0] = *(const bf16x8*)&Qb[(size_t)qrA * 64 + l4 * 8];
    qfA[1] = *(const bf16x8*)&Qb[(size_t)qrA * 64 + 32 + l4 * 8];
    qfB[0] = *(const bf16x8*)&Qb[(size_t)qrB * 64 + l4 * 8];
    qfB[1] = *(const bf16x8*)&Qb[(size_t)qrB * 64 + 32 + l4 * 8];
  }
  f32x4 oA[4] = {fz, fz, fz, fz}, oB[4] = {fz, fz, fz, fz};
  float mA = -1e30f, lsA = 0.f, mB = -1e30f, lsB = 0.f;

  // ======== phase 1: A+B on tiles 0..qtB (1 barrier/slot, proven R13) ========
  stage(0, 0);
  stage(1, 1);
  stage(2, 2);
  int cur = 0;
#pragma unroll 1
  for (int kt = 0; kt <= qtB; ++kt) {
    asm volatile("s_waitcnt vmcnt(8)" ::: "memory");
    __builtin_amdgcn_s_barrier();
    __builtin_amdgcn_sched_barrier(0);

    f32x4 sA[4] = {fz, fz, fz, fz}, sB[4] = {fz, fz, fz, fz};
    __builtin_amdgcn_s_setprio(1);
#pragma unroll
    for (int s = 0; s < 2; ++s)
#pragma unroll
      for (int nb = 0; nb < 4; ++nb) {
        int kk = nb * 16 + l15;
        int ch = (s * 4 + l4) ^ (kk & 7);
        bf16x8 kf = *(const bf16x8*)&Kl[cur][kk * 64 + ch * 8];
        sA[nb] = __builtin_amdgcn_mfma_f32_16x16x32_bf16(kf, qfA[s], sA[nb], 0, 0, 0);
        sB[nb] = __builtin_amdgcn_mfma_f32_16x16x32_bf16(kf, qfB[s], sB[nb], 0, 0, 0);
      }
    __builtin_amdgcn_s_setprio(0);

    float vA[16], vB[16];
#pragma unroll
    for (int nb = 0; nb < 4; ++nb)
#pragma unroll
      for (int r = 0; r < 4; ++r) {
        vA[nb * 4 + r] = sA[nb][r];
        vB[nb * 4 + r] = sB[nb][r];
      }
    if (kt == qtB) {
      int qg = wave * 16 + l15;
#pragma unroll
      for (int i = 0; i < 16; ++i) {
        int kg = (i >> 2) * 16 + l4 * 4 + (i & 3);
        if (kg > qg) vB[i] = -1e30f;
      }
    }
    float tA[8], tB[8];
#pragma unroll
    for (int i = 0; i < 8; ++i) {
      tA[i] = fmaxf(vA[2 * i], vA[2 * i + 1]);
      tB[i] = fmaxf(vB[2 * i], vB[2 * i + 1]);
    }
#pragma unroll
    for (int i = 0; i < 4; ++i) {
      tA[i] = fmaxf(tA[i], tA[i + 4]);
      tB[i] = fmaxf(tB[i], tB[i + 4]);
    }
    float mxA = fmaxf(fmaxf(tA[0], tA[2]), fmaxf(tA[1], tA[3]));
    float mxB = fmaxf(fmaxf(tB[0], tB[2]), fmaxf(tB[1], tB[3]));
    if (!__all(fmaxf(mxA - mA, mxB - mB) <= 8.0f)) {
      float mrA = fmaxf(mxA, __shfl_xor(mxA, 16));
      float mrB = fmaxf(mxB, __shfl_xor(mxB, 16));
      mrA = fmaxf(mrA, __shfl_xor(mrA, 32));
      mrB = fmaxf(mrB, __shfl_xor(mrB, 32));
      float mnA = fmaxf(mA, mrA), mnB = fmaxf(mB, mrB);
      float aA = ex2(mA - mnA), aB = ex2(mB - mnB);
      mA = mnA;
      mB = mnB;
      lsA *= aA;
      lsB *= aB;
#pragma unroll
      for (int hb = 0; hb < 4; ++hb)
#pragma unroll
        for (int r = 0; r < 4; ++r) {
          oA[hb][r] *= aA;
          oB[hb][r] *= aB;
        }
    }
    float pA[16], pB[16];
#pragma unroll
    for (int i = 0; i < 16; ++i) {
      pA[i] = ex2(vA[i] - mA);
      pB[i] = ex2(vB[i] - mB);
    }
    float uA[8], uB[8];
#pragma unroll
    for (int i = 0; i < 8; ++i) {
      uA[i] = pA[2 * i] + pA[2 * i + 1];
      uB[i] = pB[2 * i] + pB[2 * i + 1];
    }
#pragma unroll
    for (int i = 0; i < 4; ++i) {
      uA[i] += uA[i + 4];
      uB[i] += uB[i + 4];
    }
    lsA += (uA[0] + uA[2]) + (uA[1] + uA[3]);
    lsB += (uB[0] + uB[2]) + (uB[1] + uB[3]);
    bf16x8 pfA[2], pfB[2];
#pragma unroll
    for (int s = 0; s < 2; ++s) {
      u32x4 wa, wb;
      wa.x = cvt_pk_bf16(pA[8 * s + 0], pA[8 * s + 1]);
      wb.x = cvt_pk_bf16(pB[8 * s + 0], pB[8 * s + 1]);
      wa.y = cvt_pk_bf16(pA[8 * s + 2], pA[8 * s + 3]);
      wb.y = cvt_pk_bf16(pB[8 * s + 2], pB[8 * s + 3]);
      wa.z = cvt_pk_bf16(pA[8 * s + 4], pA[8 * s + 5]);
      wb.z = cvt_pk_bf16(pB[8 * s + 4], pB[8 * s + 5]);
      wa.w = cvt_pk_bf16(pA[8 * s + 6], pA[8 * s + 7]);
      wb.w = cvt_pk_bf16(pB[8 * s + 6], pB[8 * s + 7]);
      pfA[s] = __builtin_bit_cast(bf16x8, wa);
      pfB[s] = __builtin_bit_cast(bf16x8, wb);
    }
    // batched PV (shared vf for A and B; one lgkm wait)
    {
      bf16x8 vf[2][4];
#pragma unroll
      for (int s = 0; s < 2; ++s)
#pragma unroll
        for (int hb = 0; hb < 4; ++hb) {
          bf16x4 ta = tr16(&Vtr[cur][(hb * 16 + s * 8) * 64 + lane * 4]);
          bf16x4 tb = tr16(&Vtr[cur][(hb * 16 + s * 8 + 4) * 64 + lane * 4]);
          vf[s][hb] = __builtin_shufflevector(ta, tb, 0, 1, 2, 3, 4, 5, 6, 7);
        }
      asm volatile("s_waitcnt lgkmcnt(0)" ::: "memory");
      __builtin_amdgcn_sched_barrier(0);
      __builtin_amdgcn_s_setprio(1);
#pragma unroll
      for (int s = 0; s < 2; ++s)
#pragma unroll
        for (int hb = 0; hb < 4; ++hb) {
          oA[hb] = __builtin_amdgcn_mfma_f32_16x16x32_bf16(vf[s][hb], pfA[s], oA[hb], 0, 0, 0);
          oB[hb] = __builtin_amdgcn_mfma_f32_16x16x32_bf16(vf[s][hb], pfB[s], oB[hb], 0, 0, 0);
        }
      __builtin_amdgcn_s_setprio(0);
    }

    int nt = kt + 3 > qtB ? qtB : kt + 3;
    stage((cur + 3) & 3, nt);
    cur = (cur + 1) & 3;
  }

  // ======== phase 2: A-only, TWO tiles per slot (2 barriers/slot) ========
  const int t0 = qtB + 1;
  const int rem = qtA - qtB;
  const int nd = (rem - 1) >> 1;
  __builtin_amdgcn_s_barrier();
  __builtin_amdgcn_sched_barrier(0);
#pragma unroll
  for (int i = 0; i < 4; ++i) {
    int tt = t0 + i > qtA ? qtA : t0 + i;
    stage(i, tt);
  }

  auto smx2 = [&](f32x4* s1, f32x4* s2, bf16x8* pf1, bf16x8* pf2) {
    float v1[16], v2[16];
#pragma unroll
    for (int nb = 0; nb < 4; ++nb)
#pragma unroll
      for (int r = 0; r < 4; ++r) {
        v1[nb * 4 + r] = s1[nb][r];
        v2[nb * 4 + r] = s2[nb][r];
      }
    float t1[8], t2[8];
#pragma unroll
    for (int i = 0; i < 8; ++i) {
      t1[i] = fmaxf(v1[2 * i], v1[2 * i + 1]);
      t2[i] = fmaxf(v2[2 * i], v2[2 * i + 1]);
    }
#pragma unroll
    for (int i = 0; i < 4; ++i) {
      t1[i] = fmaxf(t1[i], t1[i + 4]);
      t2[i] = fmaxf(t2[i], t2[i + 4]);
    }
    float mx = fmaxf(fmaxf(fmaxf(t1[0], t1[2]), fmaxf(t1[1], t1[3])),
                     fmaxf(fmaxf(t2[0], t2[2]), fmaxf(t2[1], t2[3])));
    if (!__all(mx <= mA + 8.0f)) {
      float mr = fmaxf(mx, __shfl_xor(mx, 16));
      mr = fmaxf(mr, __shfl_xor(mr, 32));
      float mn = fmaxf(mA, mr);
      float a = ex2(mA - mn);
      mA = mn;
      lsA *= a;
#pragma unroll
      for (int hb = 0; hb < 4; ++hb)
#pragma unroll
        for (int r = 0; r < 4; ++r) oA[hb][r] *= a;
    }
    float p1[16], p2[16];
#pragma unroll
    for (int i = 0; i < 16; ++i) {
      p1[i] = ex2(v1[i] - mA);
      p2[i] = ex2(v2[i] - mA);
    }
    float u1[8], u2[8];
#pragma unroll
    for (int i = 0; i < 8; ++i) {
      u1[i] = p1[2 * i] + p1[2 * i + 1];
      u2[i] = p2[2 * i] + p2[2 * i + 1];
    }
#pragma unroll
    for (int i = 0; i < 4; ++i) {
      u1[i] += u1[i + 4];
      u2[i] += u2[i + 4];
    }
    lsA += (u1[0] + u1[2]) + (u1[1] + u1[3]) + (u2[0] + u2[2]) + (u2[1] + u2[3]);
#pragma unroll
    for (int s = 0; s < 2; ++s) {
      u32x4 w1, w2;
      w1.x = cvt_pk_bf16(p1[8 * s + 0], p1[8 * s + 1]);
      w2.x = cvt_pk_bf16(p2[8 * s + 0], p2[8 * s + 1]);
      w1.y = cvt_pk_bf16(p1[8 * s + 2], p1[8 * s + 3]);
      w2.y = cvt_pk_bf16(p2[8 * s + 2], p2[8 * s + 3]);
      w1.z = cvt_pk_bf16(p1[8 * s + 4], p1[8 * s + 5]);
      w2.z = cvt_pk_bf16(p2[8 * s + 4], p2[8 * s + 5]);
      w1.w = cvt_pk_bf16(p1[8 * s + 6], p1[8 * s + 7]);
      w2.w = cvt_pk_bf16(p2[8 * s + 6], p2[8 * s + 7]);
      pf1[s] = __builtin_bit_cast(bf16x8, w1);
      pf2[s] = __builtin_bit_cast(bf16x8, w2);
    }
  };

#pragma unroll 1
  for (int j2 = 0; j2 < nd; ++j2) {
    asm volatile("s_waitcnt vmcnt(8)" ::: "memory");
    __builtin_amdgcn_s_barrier();
    __builtin_amdgcn_sched_barrier(0);
    int b0 = (2 * j2) & 3, b1 = (2 * j2 + 1) & 3;

    f32x4 s1[4] = {fz, fz, fz, fz}, s2[4] = {fz, fz, fz, fz};
    __builtin_amdgcn_s_setprio(1);
    qk(b0, qfA, s1);
    qk(b1, qfA, s2);
    __builtin_amdgcn_s_setprio(0);
    bf16x8 pf1[2], pf2[2];
    smx2(s1, s2, pf1, pf2);
    pv(b0, pf1, oA);
    pv(b1, pf2, oA);

    __builtin_amdgcn_s_barrier();
    __builtin_amdgcn_sched_barrier(0);
    int ta = t0 + 2 * j2 + 4, tb2 = t0 + 2 * j2 + 5;
    stage(b0, ta > qtA ? qtA : ta);
    stage(b1, tb2 > qtA ? qtA : tb2);
  }

  {
    asm volatile("s_waitcnt vmcnt(8)" ::: "memory");
    __builtin_amdgcn_s_barrier();
    __builtin_amdgcn_sched_barrier(0);
    int buf = (rem - 1) & 3;
    f32x4 sA[4] = {fz, fz, fz, fz};
    __builtin_amdgcn_s_setprio(1);
    qk(buf, qfA, sA);
    __builtin_amdgcn_s_setprio(0);
    float vA[16];
#pragma unroll
    for (int nb = 0; nb < 4; ++nb)
#pragma unroll
      for (int r = 0; r < 4; ++r) vA[nb * 4 + r] = sA[nb][r];
    int qg = wave * 16 + l15;
#pragma unroll
    for (int i = 0; i < 16; ++i) {
      int kg = (i >> 2) * 16 + l4 * 4 + (i & 3);
      if (kg > qg) vA[i] = -1e30f;
    }
    float tA[8];
#pragma unroll
    for (int i = 0; i < 8; ++i) tA[i] = fmaxf(vA[2 * i], vA[2 * i + 1]);
#pragma unroll
    for (int i = 0; i < 4; ++i) tA[i] = fmaxf(tA[i], tA[i + 4]);
    float mxA = fmaxf(fmaxf(tA[0], tA[2]), fmaxf(tA[1], tA[3]));
    if (!__all(mxA <= mA + 8.0f)) {
      float mrA = fmaxf(mxA, __shfl_xor(mxA, 16));
      mrA = fmaxf(mrA, __shfl_xor(mrA, 32));
      float mnA = fmaxf(mA, mrA);
      float aA = ex2(mA - mnA);
      mA = mnA;
      lsA *= aA;
#pragma unroll
      for (int hb = 0; hb < 4; ++hb)
#pragma unroll
        for (int r = 0; r < 4; ++r) oA[hb][r] *= aA;
    }
    float pA[16];
#pragma unroll
    for (int i = 0; i < 16; ++i) pA[i] = ex2(vA[i] - mA);
    float uA[8];
#pragma unroll
    for (int i = 0; i < 8; ++i) uA[i] = pA[2 * i] + pA[2 * i + 1];
#pragma unroll
    for (int i = 0; i < 4; ++i) uA[i] += uA[i + 4];
    lsA += (uA[0] + uA[2]) + (uA[1] + uA[3]);
    bf16x8 pfA[2];
#pragma unroll
    for (int s = 0; s < 2; ++s) {
      u32x4 wa;
      wa.x = cvt_pk_bf16(pA[8 * s + 0], pA[8 * s + 1]);
      wa.y = cvt_pk_bf16(pA[8 * s + 2], pA[8 * s + 3]);
      wa.z = cvt_pk_bf16(pA[8 * s + 4], pA[8 * s + 5]);
      wa.w = cvt_pk_bf16(pA[8 * s + 6], pA[8 * s + 7]);
      pfA[s] = __builtin_bit_cast(bf16x8, wa);
    }
    pv(buf, pfA, oA);
  }

  auto epi = [&](f32x4* accO, float lsum, int qt) {
    float t = lsum + __shfl_xor(lsum, 16);
    t += __shfl_xor(t, 32);
    float inv = 1.0f / t;
    int qg = qt * 64 + wave * 16 + l15;
    u16* yrow = Y + (size_t)(b * 2048 + qg) * 1024 + h * 64;
#pragma unroll
    for (int hb = 0; hb < 4; ++hb) {
      uint2 pk;
      pk.x = cvt_pk_bf16(accO[hb][0] * inv, accO[hb][1] * inv);
      pk.y = cvt_pk_bf16(accO[hb][2] * inv, accO[hb][3] * inv);
      *(uint2*)&yrow[hb * 16 + l4 * 4] = pk;
    }
  };
  epi(oA, lsA, qtA);
  epi(oB, lsB, qtB);
}

extern "C" void kernel_launch(void* const* d_in, const int* in_sizes, int n_in,
                              void* d_out, int out_size, void* d_ws, size_t ws_size,
                              hipStream_t stream) {
  const float* x = (const float*)d_in[0];       // [2,2048,1024]
  const float* Wqkv = (const float*)d_in[1];    // [1024,3072]
  const float* Wproj = (const float*)d_in[2];   // [1024,1024]
  float* out = (float*)d_out;                   // [2,2048,1024] f32

  char* ws = (char*)d_ws;
  u16* Xb  = (u16*)(ws + 0);                    // 8 MB  [4096][1024]
  u16* Wqt = (u16*)(ws + ((size_t)8 << 20));    // 6 MB  [3072][1024]
  u16* Wpt = (u16*)(ws + ((size_t)14 << 20));   // 2 MB  [1024][1024]
  u16* Qs  = (u16*)(ws + ((size_t)16 << 20));   // 8 MB  [2,16,2048,64]
  u16* Ks  = (u16*)(ws + ((size_t)24 << 20));   // 8 MB
  u16* Vs  = (u16*)(ws + ((size_t)32 << 20));   // 8 MB
  u16* Yb  = (u16*)(ws + ((size_t)40 << 20));   // 8 MB  [4096][1024]

  k_prep<<<6144, 256, 0, stream>>>(x, Xb, Wqkv, Wqt, Wproj, Wpt);
  k_gemm0<<<dim3(24, 32), 256, 0, stream>>>(Xb, Wqt, Qs, Ks, Vs, 1024);
  k_attn<<<dim3(16, 32), 256, 0, stream>>>(Qs, Ks, Vs, Yb);
  k_gemm1<<<dim3(16, 32), 256, 0, stream>>>(Yb, Wpt, out, 1024);
}